// Round 2
// baseline (1685.987 us; speedup 1.0000x reference)
//
#include <hip/hip_runtime.h>
#include <hip/hip_bf16.h>

#define NNODES 50000
#define NEDGES 1600000
#define FNODE 32
#define FEDGE 8
#define HIDD 256
#define NGRAPH 64
#define GDIM 16
#define NACT 64
#define FEATD (HIDD + GDIM) // 272

// ---------------- bf16 helpers ----------------

__device__ inline float bfl(uint u) {  // low 16 bits -> float
  union { uint i; float f; } v; v.i = u << 16; return v.f;
}
__device__ inline float bfh(uint u) {  // high 16 bits -> float
  union { uint i; float f; } v; v.i = u & 0xffff0000u; return v.f;
}
__device__ inline float bf1(ushort u) {
  union { uint i; float f; } v; v.i = ((uint)u) << 16; return v.f;
}
__device__ inline ushort f2b(float a) {
  __hip_bfloat16 h = __float2bfloat16(a);  // RNE
  return *(ushort*)&h;
}
__device__ inline uint packbf(float a, float b) {
  return (uint)f2b(a) | ((uint)f2b(b) << 16);
}

// ---------------- CSR build ----------------

__global__ void k_zero_i32(int* __restrict__ p, int n) {
  int i = blockIdx.x * blockDim.x + threadIdx.x;
  if (i < n) p[i] = 0;
}

__global__ void k_hist(const int* __restrict__ dst, int* __restrict__ off) {
  int e = blockIdx.x * blockDim.x + threadIdx.x;
  if (e < NEDGES) atomicAdd(&off[dst[e] + 1], 1);
}

__global__ void k_scan1(int* __restrict__ data, int n, int* __restrict__ sums) {
  __shared__ int buf[1024];
  int gid = blockIdx.x * 1024 + threadIdx.x;
  int v = (gid < n) ? data[gid] : 0;
  buf[threadIdx.x] = v;
  __syncthreads();
  for (int d = 1; d < 1024; d <<= 1) {
    int t = (threadIdx.x >= d) ? buf[threadIdx.x - d] : 0;
    __syncthreads();
    buf[threadIdx.x] += t;
    __syncthreads();
  }
  if (gid < n) data[gid] = buf[threadIdx.x];
  if (threadIdx.x == 1023) sums[blockIdx.x] = buf[1023];
}

__global__ void k_scan2(int* __restrict__ sums, int nb) {
  int run = 0;
  for (int i = 0; i < nb; ++i) { run += sums[i]; sums[i] = run; }
}

__global__ void k_scan3(int* __restrict__ data, int n, const int* __restrict__ sums) {
  int gid = blockIdx.x * 1024 + threadIdx.x;
  if (blockIdx.x > 0 && gid < n) data[gid] += sums[blockIdx.x - 1];
}

__global__ void k_copy_i32(const int* __restrict__ a, int* __restrict__ b, int n) {
  int i = blockIdx.x * blockDim.x + threadIdx.x;
  if (i < n) b[i] = a[i];
}

__global__ void k_scatter(const int* __restrict__ src, const int* __restrict__ dst,
                          int* __restrict__ cur, int2* __restrict__ csr) {
  int e = blockIdx.x * blockDim.x + threadIdx.x;
  if (e >= NEDGES) return;
  int d = dst[e];
  int pos = atomicAdd(&cur[d], 1);
  csr[pos] = make_int2(src[e], e);
}

// ---------------- x -> bf16 ----------------

__global__ void k_cvt_x(const float* __restrict__ x, ushort* __restrict__ xb) {
  int i = blockIdx.x * blockDim.x + threadIdx.x;  // one float4 per thread
  if (i >= NNODES * FNODE / 4) return;
  float4 v = *(const float4*)&x[(size_t)i * 4];
  uint2 o;
  o.x = packbf(v.x, v.y);
  o.y = packbf(v.z, v.w);
  *(uint2*)&xb[(size_t)i * 4] = o;
}

// ---------------- Layer 0 edge pull (d=32), x gathered as bf16 ----------------

__global__ void k_edge32(const float* __restrict__ x, const ushort* __restrict__ xb,
                         const float* __restrict__ ea, const float* __restrict__ We0,
                         const int* __restrict__ off, const int2* __restrict__ csr,
                         float* __restrict__ t0) {
  int wid = (blockIdx.x * blockDim.x + threadIdx.x) >> 6;
  if (wid >= NNODES) return;
  int lane = threadIdx.x & 63;
  int j = lane >> 5;
  int c = lane & 31;
  float we[FEDGE];
#pragma unroll
  for (int k = 0; k < FEDGE; ++k) we[k] = We0[k * FNODE + c];
  int s0 = off[wid], s1 = off[wid + 1];
  float acc = 0.f;
  for (int e = s0 + j; e < s1; e += 2) {
    int2 p = csr[e];
    float hs = bf1(xb[(size_t)p.x * FNODE + c]);
    const float4 e0 = *(const float4*)&ea[(size_t)p.y * FEDGE];
    const float4 e1 = *(const float4*)&ea[(size_t)p.y * FEDGE + 4];
    float pr = hs;
    pr = fmaf(e0.x, we[0], pr);
    pr = fmaf(e0.y, we[1], pr);
    pr = fmaf(e0.z, we[2], pr);
    pr = fmaf(e0.w, we[3], pr);
    pr = fmaf(e1.x, we[4], pr);
    pr = fmaf(e1.y, we[5], pr);
    pr = fmaf(e1.z, we[6], pr);
    pr = fmaf(e1.w, we[7], pr);
    acc += fmaxf(pr, 0.f);
  }
  acc += __shfl_xor(acc, 32);
  if (j == 0) t0[wid * FNODE + c] = x[wid * FNODE + c] + acc;
}

// ---------------- Layers 1-3 edge pull (d=256), h gathered as bf16 ------------

__device__ inline void edge_body(int2 p, const ushort* __restrict__ hb,
                                 const float* __restrict__ ea, int c,
                                 const float4* wef, float4& acc) {
  uint2 hu = *(const uint2*)&hb[(size_t)p.x * HIDD + c];
  const float4 e0 = *(const float4*)&ea[(size_t)p.y * FEDGE];
  const float4 e1 = *(const float4*)&ea[(size_t)p.y * FEDGE + 4];
  float4 pr;
  pr.x = bfl(hu.x);
  pr.y = bfh(hu.x);
  pr.z = bfl(hu.y);
  pr.w = bfh(hu.y);
#define ACCK(ev, kk)                      \
  pr.x = fmaf(ev, wef[kk].x, pr.x);       \
  pr.y = fmaf(ev, wef[kk].y, pr.y);       \
  pr.z = fmaf(ev, wef[kk].z, pr.z);       \
  pr.w = fmaf(ev, wef[kk].w, pr.w);
  ACCK(e0.x, 0) ACCK(e0.y, 1) ACCK(e0.z, 2) ACCK(e0.w, 3)
  ACCK(e1.x, 4) ACCK(e1.y, 5) ACCK(e1.z, 6) ACCK(e1.w, 7)
#undef ACCK
  acc.x += fmaxf(pr.x, 0.f);
  acc.y += fmaxf(pr.y, 0.f);
  acc.z += fmaxf(pr.z, 0.f);
  acc.w += fmaxf(pr.w, 0.f);
}

__global__ void k_edge256(const ushort* __restrict__ hb, const float* __restrict__ ea,
                          const float* __restrict__ Wel, const int* __restrict__ off,
                          const int2* __restrict__ csr, float* __restrict__ t) {
  int wid = (blockIdx.x * blockDim.x + threadIdx.x) >> 6;
  if (wid >= NNODES) return;
  int lane = threadIdx.x & 63;
  int c = lane * 4;
  float4 wef[FEDGE];
#pragma unroll
  for (int k = 0; k < FEDGE; ++k) wef[k] = *(const float4*)&Wel[k * HIDD + c];
  int s0 = off[wid], s1 = off[wid + 1];
  float4 acc = {0.f, 0.f, 0.f, 0.f};
  int e = s0;
  for (; e + 2 <= s1; e += 2) {  // 2-edge unroll: both gathers issue together
    int2 p0 = csr[e];
    int2 p1 = csr[e + 1];
    edge_body(p0, hb, ea, c, wef, acc);
    edge_body(p1, hb, ea, c, wef, acc);
  }
  if (e < s1) edge_body(csr[e], hb, ea, c, wef, acc);

  uint2 su = *(const uint2*)&hb[(size_t)wid * HIDD + c];  // self term (bf16)
  float4 o;
  o.x = bfl(su.x) + acc.x;
  o.y = bfh(su.x) + acc.y;
  o.z = bfl(su.y) + acc.z;
  o.w = bfh(su.y) + acc.w;
  *(float4*)&t[(size_t)wid * HIDD + c] = o;
}

// -------- Node update GEMM: hb = relu(T @ W + b) written as bf16 --------

template <int K>
__global__ __launch_bounds__(256) void k_gemm_relu(const float* __restrict__ T,
                                                   const float* __restrict__ W,
                                                   const float* __restrict__ bias,
                                                   ushort* __restrict__ outb, int nrows) {
  __shared__ float tl[32][K];
  const int r0 = blockIdx.x * 32;
  const int tid = threadIdx.x;
  const int KV = K / 4;
  for (int i = tid; i < 32 * KV; i += 256) {
    int row = i / KV;
    int kk = (i - row * KV) * 4;
    float4 v = {0.f, 0.f, 0.f, 0.f};
    if (r0 + row < nrows) v = *(const float4*)&T[(size_t)(r0 + row) * K + kk];
    *(float4*)&tl[row][kk] = v;
  }
  __syncthreads();
  const int c = (tid & 63) * 4;
  const int rg = (tid >> 6) * 8;
  float4 acc[8];
#pragma unroll
  for (int r = 0; r < 8; ++r) acc[r] = make_float4(0.f, 0.f, 0.f, 0.f);
  for (int k = 0; k < K; ++k) {
    const float4 w = *(const float4*)&W[k * HIDD + c];
#pragma unroll
    for (int r = 0; r < 8; ++r) {
      float tv = tl[rg + r][k];
      acc[r].x = fmaf(tv, w.x, acc[r].x);
      acc[r].y = fmaf(tv, w.y, acc[r].y);
      acc[r].z = fmaf(tv, w.z, acc[r].z);
      acc[r].w = fmaf(tv, w.w, acc[r].w);
    }
  }
  const float4 bb = *(const float4*)&bias[c];
#pragma unroll
  for (int r = 0; r < 8; ++r) {
    int row = r0 + rg + r;
    if (row < nrows) {
      uint2 o;
      o.x = packbf(fmaxf(acc[r].x + bb.x, 0.f), fmaxf(acc[r].y + bb.y, 0.f));
      o.y = packbf(fmaxf(acc[r].z + bb.z, 0.f), fmaxf(acc[r].w + bb.w, 0.f));
      *(uint2*)&outb[(size_t)row * HIDD + c] = o;
    }
  }
}

// ---------------- Mean pool per graph (batch sorted, h in bf16) ---------------

__global__ void k_pool(const ushort* __restrict__ hb, const int* __restrict__ batch,
                       const float* __restrict__ gf, float* __restrict__ feats) {
  int b = blockIdx.x;
  __shared__ int srange[2];
  if (threadIdx.x < 2) {
    int target = b + threadIdx.x;
    int lo = 0, hi = NNODES;
    while (lo < hi) {
      int mid = (lo + hi) >> 1;
      if (batch[mid] < target) lo = mid + 1; else hi = mid;
    }
    srange[threadIdx.x] = lo;
  }
  __syncthreads();
  int s = srange[0], e = srange[1];
  int col = threadIdx.x;  // 256 threads = 256 cols
  float acc = 0.f;
  for (int n = s; n < e; ++n) acc += bf1(hb[(size_t)n * HIDD + col]);
  float cnt = fmaxf((float)(e - s), 1.0f);
  feats[b * FEATD + col] = acc / cnt;
  if (threadIdx.x < GDIM) feats[b * FEATD + HIDD + threadIdx.x] = gf[b * GDIM + threadIdx.x];
}

// ---------------- Heads: logits [B,64] then value [B] ----------------

__global__ void k_heads(const float* __restrict__ feats, const float* __restrict__ Wp,
                        const float* __restrict__ bp, const float* __restrict__ Wv,
                        const float* __restrict__ bv, float* __restrict__ out) {
  int b = blockIdx.x;
  int t = threadIdx.x;  // 64 threads = 1 wave
  __shared__ float f[FEATD];
  for (int i = t; i < FEATD; i += 64) f[i] = feats[b * FEATD + i];
  __syncthreads();
  float acc = bp[t];
  for (int k = 0; k < FEATD; ++k) acc = fmaf(f[k], Wp[k * NACT + t], acc);
  out[b * NACT + t] = acc;
  float pv = 0.f;
  for (int k = t; k < FEATD; k += 64) pv = fmaf(f[k], Wv[k], pv);
#pragma unroll
  for (int d = 32; d > 0; d >>= 1) pv += __shfl_down(pv, d);
  if (t == 0) out[NGRAPH * NACT + b] = pv + bv[0];
}

// ---------------- launch ----------------

extern "C" void kernel_launch(void* const* d_in, const int* in_sizes, int n_in,
                              void* d_out, int out_size, void* d_ws, size_t ws_size,
                              hipStream_t stream) {
  const float* x   = (const float*)d_in[0];
  const float* ea  = (const float*)d_in[1];
  const float* gf  = (const float*)d_in[2];
  const float* We0 = (const float*)d_in[3];
  const float* W0  = (const float*)d_in[4];
  const float* b0  = (const float*)d_in[5];
  const float* We  = (const float*)d_in[6];
  const float* W   = (const float*)d_in[7];
  const float* bb  = (const float*)d_in[8];
  const float* Wp  = (const float*)d_in[9];
  const float* bp  = (const float*)d_in[10];
  const float* Wv  = (const float*)d_in[11];
  const float* bv  = (const float*)d_in[12];
  const int* eidx  = (const int*)d_in[13];
  const int* batch = (const int*)d_in[14];
  const int* esrc = eidx;
  const int* edst = eidx + NEDGES;

  char* w = (char*)d_ws;
  size_t p = 0;
  auto take = [&](size_t bytes) {
    size_t r = p;
    p += (bytes + 255) & ~(size_t)255;
    return r;
  };
  int* off     = (int*)(w + take((NNODES + 1) * 4));
  int* cur     = (int*)(w + take(NNODES * 4));
  int* sums    = (int*)(w + take(1024));
  int2* csr    = (int2*)(w + take((size_t)NEDGES * 8));
  float* t0    = (float*)(w + take((size_t)NNODES * FNODE * 4));
  ushort* xb   = (ushort*)(w + take((size_t)NNODES * FNODE * 2));
  float* tbuf  = (float*)(w + take((size_t)NNODES * HIDD * 4));
  ushort* hb   = (ushort*)(w + take((size_t)NNODES * HIDD * 2));
  float* feats = (float*)(w + take((size_t)NGRAPH * FEATD * 4));
  if (p > ws_size) return;  // workspace too small -> visible failure

  // CSR by dst
  k_zero_i32<<<(NNODES + 1 + 255) / 256, 256, 0, stream>>>(off, NNODES + 1);
  k_hist<<<(NEDGES + 255) / 256, 256, 0, stream>>>(edst, off);
  int n_scan = NNODES + 1;
  int nb_scan = (n_scan + 1023) / 1024;
  k_scan1<<<nb_scan, 1024, 0, stream>>>(off, n_scan, sums);
  k_scan2<<<1, 1, 0, stream>>>(sums, nb_scan);
  k_scan3<<<nb_scan, 1024, 0, stream>>>(off, n_scan, sums);
  k_copy_i32<<<(NNODES + 255) / 256, 256, 0, stream>>>(off, cur, NNODES);
  k_scatter<<<(NEDGES + 255) / 256, 256, 0, stream>>>(esrc, edst, cur, csr);

  // x -> bf16 for the layer-0 gather
  k_cvt_x<<<(NNODES * FNODE / 4 + 255) / 256, 256, 0, stream>>>(x, xb);

  // layer 0
  k_edge32<<<NNODES / 4, 256, 0, stream>>>(x, xb, ea, We0, off, csr, t0);
  k_gemm_relu<FNODE><<<(NNODES + 31) / 32, 256, 0, stream>>>(t0, W0, b0, hb, NNODES);

  // layers 1..3: edge pull (bf16 gather) -> fp32 t -> GEMM -> bf16 h
  for (int l = 0; l < 3; ++l) {
    k_edge256<<<NNODES / 4, 256, 0, stream>>>(hb, ea, We + (size_t)l * FEDGE * HIDD, off,
                                              csr, tbuf);
    k_gemm_relu<HIDD><<<(NNODES + 31) / 32, 256, 0, stream>>>(
        tbuf, W + (size_t)l * HIDD * HIDD, bb + (size_t)l * HIDD, hb, NNODES);
  }

  // pool + heads
  k_pool<<<NGRAPH, HIDD, 0, stream>>>(hb, batch, gf, feats);
  k_heads<<<NGRAPH, 64, 0, stream>>>(feats, Wp, bp, Wv, bv, (float*)d_out);
}

// Round 3
// 1070.579 us; speedup vs baseline: 1.5748x; 1.5748x over previous
//
#include <hip/hip_runtime.h>
#include <hip/hip_bf16.h>

#define NNODES 50000
#define NEDGES 1600000
#define FNODE 32
#define FEDGE 8
#define HIDD 256
#define NGRAPH 64
#define GDIM 16
#define NACT 64
#define FEATD (HIDD + GDIM) // 272
#define PCH 8               // pool chunks per graph

// ---------------- bf16 helpers ----------------

__device__ inline float bfl(uint u) {  // low 16 bits -> float
  union { uint i; float f; } v; v.i = u << 16; return v.f;
}
__device__ inline float bfh(uint u) {  // high 16 bits -> float
  union { uint i; float f; } v; v.i = u & 0xffff0000u; return v.f;
}
__device__ inline float bf1(ushort u) {
  union { uint i; float f; } v; v.i = ((uint)u) << 16; return v.f;
}
__device__ inline ushort f2b(float a) {
  __hip_bfloat16 h = __float2bfloat16(a);  // RNE
  return *(ushort*)&h;
}
__device__ inline uint packbf(float a, float b) {
  return (uint)f2b(a) | ((uint)f2b(b) << 16);
}

// ---------------- CSR build ----------------

__global__ void k_zero_i32(int* __restrict__ p, int n) {
  int i = blockIdx.x * blockDim.x + threadIdx.x;
  if (i < n) p[i] = 0;
}

__global__ void k_hist(const int* __restrict__ dst, int* __restrict__ off) {
  int e = blockIdx.x * blockDim.x + threadIdx.x;
  if (e < NEDGES) atomicAdd(&off[dst[e] + 1], 1);
}

__global__ void k_scan1(int* __restrict__ data, int n, int* __restrict__ sums) {
  __shared__ int buf[1024];
  int gid = blockIdx.x * 1024 + threadIdx.x;
  int v = (gid < n) ? data[gid] : 0;
  buf[threadIdx.x] = v;
  __syncthreads();
  for (int d = 1; d < 1024; d <<= 1) {
    int t = (threadIdx.x >= d) ? buf[threadIdx.x - d] : 0;
    __syncthreads();
    buf[threadIdx.x] += t;
    __syncthreads();
  }
  if (gid < n) data[gid] = buf[threadIdx.x];
  if (threadIdx.x == 1023) sums[blockIdx.x] = buf[1023];
}

__global__ void k_scan2(int* __restrict__ sums, int nb) {
  int run = 0;
  for (int i = 0; i < nb; ++i) { run += sums[i]; sums[i] = run; }
}

__global__ void k_scan3(int* __restrict__ data, int n, const int* __restrict__ sums) {
  int gid = blockIdx.x * 1024 + threadIdx.x;
  if (blockIdx.x > 0 && gid < n) data[gid] += sums[blockIdx.x - 1];
}

__global__ void k_copy_i32(const int* __restrict__ a, int* __restrict__ b, int n) {
  int i = blockIdx.x * blockDim.x + threadIdx.x;
  if (i < n) b[i] = a[i];
}

// scatter edges into CSR order; also reorder edge_attr into CSR order as bf16
__global__ void k_scatter(const int* __restrict__ src, const int* __restrict__ dst,
                          int* __restrict__ cur, const float* __restrict__ ea,
                          int* __restrict__ csr_src, ushort* __restrict__ eab) {
  int e = blockIdx.x * blockDim.x + threadIdx.x;
  if (e >= NEDGES) return;
  int d = dst[e];
  int pos = atomicAdd(&cur[d], 1);
  csr_src[pos] = src[e];
  float4 a = *(const float4*)&ea[(size_t)e * FEDGE];
  float4 b = *(const float4*)&ea[(size_t)e * FEDGE + 4];
  uint4 o;
  o.x = packbf(a.x, a.y);
  o.y = packbf(a.z, a.w);
  o.z = packbf(b.x, b.y);
  o.w = packbf(b.z, b.w);
  *(uint4*)&eab[(size_t)pos * FEDGE] = o;
}

// ---------------- x -> bf16 ----------------

__global__ void k_cvt_x(const float* __restrict__ x, ushort* __restrict__ xb) {
  int i = blockIdx.x * blockDim.x + threadIdx.x;  // one float4 per thread
  if (i >= NNODES * FNODE / 4) return;
  float4 v = *(const float4*)&x[(size_t)i * 4];
  uint2 o;
  o.x = packbf(v.x, v.y);
  o.y = packbf(v.z, v.w);
  *(uint2*)&xb[(size_t)i * 4] = o;
}

// ---------------- Layer 0 edge pull (d=32) ----------------
// one wave per node; lanes split: j=lane>>5 handles alternate edges, c=lane&31

__device__ inline float body32(ushort hu, uint4 eu, const float* __restrict__ we) {
  float pr = bf1(hu);
  pr = fmaf(bfl(eu.x), we[0], pr);
  pr = fmaf(bfh(eu.x), we[1], pr);
  pr = fmaf(bfl(eu.y), we[2], pr);
  pr = fmaf(bfh(eu.y), we[3], pr);
  pr = fmaf(bfl(eu.z), we[4], pr);
  pr = fmaf(bfh(eu.z), we[5], pr);
  pr = fmaf(bfl(eu.w), we[6], pr);
  pr = fmaf(bfh(eu.w), we[7], pr);
  return fmaxf(pr, 0.f);
}

__global__ __launch_bounds__(256) void k_edge32(
    const float* __restrict__ x, const ushort* __restrict__ xb,
    const ushort* __restrict__ eab, const float* __restrict__ We0,
    const int* __restrict__ off, const int* __restrict__ csr_src,
    float* __restrict__ t0) {
  int wid = (blockIdx.x * blockDim.x + threadIdx.x) >> 6;
  if (wid >= NNODES) return;
  int lane = threadIdx.x & 63;
  int j = lane >> 5;
  int c = lane & 31;
  float we[FEDGE];
#pragma unroll
  for (int k = 0; k < FEDGE; ++k) we[k] = We0[k * FNODE + c];
  int s0 = off[wid], s1 = off[wid + 1];
  float acc = 0.f;
  int e = s0 + j;
  for (; e + 6 < s1; e += 8) {  // 4 edges per half-wave in flight
    int sA = csr_src[e], sB = csr_src[e + 2], sC = csr_src[e + 4], sD = csr_src[e + 6];
    ushort hA = xb[(size_t)sA * FNODE + c];
    ushort hB = xb[(size_t)sB * FNODE + c];
    ushort hC = xb[(size_t)sC * FNODE + c];
    ushort hD = xb[(size_t)sD * FNODE + c];
    uint4 eA = *(const uint4*)&eab[(size_t)e * FEDGE];
    uint4 eB = *(const uint4*)&eab[(size_t)(e + 2) * FEDGE];
    uint4 eC = *(const uint4*)&eab[(size_t)(e + 4) * FEDGE];
    uint4 eD = *(const uint4*)&eab[(size_t)(e + 6) * FEDGE];
    acc += body32(hA, eA, we);
    acc += body32(hB, eB, we);
    acc += body32(hC, eC, we);
    acc += body32(hD, eD, we);
  }
  for (; e < s1; e += 2) {
    int s = csr_src[e];
    ushort hu = xb[(size_t)s * FNODE + c];
    uint4 eu = *(const uint4*)&eab[(size_t)e * FEDGE];
    acc += body32(hu, eu, we);
  }
  acc += __shfl_xor(acc, 32);
  if (j == 0) t0[wid * FNODE + c] = x[wid * FNODE + c] + acc;
}

// ---------------- Layers 1-3 edge pull (d=256), 8-deep pipeline --------------

__device__ inline void body256(uint2 hu, uint4 eu, const float4* __restrict__ wef,
                               float4& acc) {
  float4 pr;
  pr.x = bfl(hu.x);
  pr.y = bfh(hu.x);
  pr.z = bfl(hu.y);
  pr.w = bfh(hu.y);
  float ev0 = bfl(eu.x), ev1 = bfh(eu.x), ev2 = bfl(eu.y), ev3 = bfh(eu.y);
  float ev4 = bfl(eu.z), ev5 = bfh(eu.z), ev6 = bfl(eu.w), ev7 = bfh(eu.w);
#define ACCK(ev, kk)                      \
  pr.x = fmaf(ev, wef[kk].x, pr.x);       \
  pr.y = fmaf(ev, wef[kk].y, pr.y);       \
  pr.z = fmaf(ev, wef[kk].z, pr.z);       \
  pr.w = fmaf(ev, wef[kk].w, pr.w);
  ACCK(ev0, 0) ACCK(ev1, 1) ACCK(ev2, 2) ACCK(ev3, 3)
  ACCK(ev4, 4) ACCK(ev5, 5) ACCK(ev6, 6) ACCK(ev7, 7)
#undef ACCK
  acc.x += fmaxf(pr.x, 0.f);
  acc.y += fmaxf(pr.y, 0.f);
  acc.z += fmaxf(pr.z, 0.f);
  acc.w += fmaxf(pr.w, 0.f);
}

__global__ __launch_bounds__(256) void k_edge256(
    const ushort* __restrict__ hb, const ushort* __restrict__ eab,
    const float* __restrict__ Wel, const int* __restrict__ off,
    const int* __restrict__ csr_src, float* __restrict__ t) {
  int wid = (blockIdx.x * blockDim.x + threadIdx.x) >> 6;
  if (wid >= NNODES) return;
  int lane = threadIdx.x & 63;
  int c = lane * 4;
  float4 wef[FEDGE];
#pragma unroll
  for (int k = 0; k < FEDGE; ++k) wef[k] = *(const float4*)&Wel[k * HIDD + c];
  int s0 = off[wid], s1 = off[wid + 1];
  float4 acc0 = {0.f, 0.f, 0.f, 0.f}, acc1 = {0.f, 0.f, 0.f, 0.f};
  int e = s0;
  // align e to 4 so csr_src can be read as int4
  for (; e < s1 && (e & 3); ++e) {
    int s = csr_src[e];
    uint2 hu = *(const uint2*)&hb[(size_t)s * HIDD + c];
    uint4 eu = *(const uint4*)&eab[(size_t)e * FEDGE];
    body256(hu, eu, wef, acc0);
  }
  // 8 h-gathers in flight
  for (; e + 8 <= s1; e += 8) {
    int4 sa = *(const int4*)&csr_src[e];
    int4 sb = *(const int4*)&csr_src[e + 4];
    uint2 h0 = *(const uint2*)&hb[(size_t)sa.x * HIDD + c];
    uint2 h1 = *(const uint2*)&hb[(size_t)sa.y * HIDD + c];
    uint2 h2 = *(const uint2*)&hb[(size_t)sa.z * HIDD + c];
    uint2 h3 = *(const uint2*)&hb[(size_t)sa.w * HIDD + c];
    uint2 h4 = *(const uint2*)&hb[(size_t)sb.x * HIDD + c];
    uint2 h5 = *(const uint2*)&hb[(size_t)sb.y * HIDD + c];
    uint2 h6 = *(const uint2*)&hb[(size_t)sb.z * HIDD + c];
    uint2 h7 = *(const uint2*)&hb[(size_t)sb.w * HIDD + c];
    uint4 e0 = *(const uint4*)&eab[(size_t)(e + 0) * FEDGE];
    uint4 e1 = *(const uint4*)&eab[(size_t)(e + 1) * FEDGE];
    uint4 e2 = *(const uint4*)&eab[(size_t)(e + 2) * FEDGE];
    uint4 e3 = *(const uint4*)&eab[(size_t)(e + 3) * FEDGE];
    uint4 e4 = *(const uint4*)&eab[(size_t)(e + 4) * FEDGE];
    uint4 e5 = *(const uint4*)&eab[(size_t)(e + 5) * FEDGE];
    uint4 e6 = *(const uint4*)&eab[(size_t)(e + 6) * FEDGE];
    uint4 e7 = *(const uint4*)&eab[(size_t)(e + 7) * FEDGE];
    body256(h0, e0, wef, acc0);
    body256(h1, e1, wef, acc1);
    body256(h2, e2, wef, acc0);
    body256(h3, e3, wef, acc1);
    body256(h4, e4, wef, acc0);
    body256(h5, e5, wef, acc1);
    body256(h6, e6, wef, acc0);
    body256(h7, e7, wef, acc1);
  }
  for (; e + 2 <= s1; e += 2) {
    int sA = csr_src[e], sB = csr_src[e + 1];
    uint2 hA = *(const uint2*)&hb[(size_t)sA * HIDD + c];
    uint2 hB = *(const uint2*)&hb[(size_t)sB * HIDD + c];
    uint4 eA = *(const uint4*)&eab[(size_t)e * FEDGE];
    uint4 eB = *(const uint4*)&eab[(size_t)(e + 1) * FEDGE];
    body256(hA, eA, wef, acc0);
    body256(hB, eB, wef, acc1);
  }
  if (e < s1) {
    int s = csr_src[e];
    uint2 hu = *(const uint2*)&hb[(size_t)s * HIDD + c];
    uint4 eu = *(const uint4*)&eab[(size_t)e * FEDGE];
    body256(hu, eu, wef, acc0);
  }

  uint2 su = *(const uint2*)&hb[(size_t)wid * HIDD + c];  // self term (bf16)
  float4 o;
  o.x = bfl(su.x) + acc0.x + acc1.x;
  o.y = bfh(su.x) + acc0.y + acc1.y;
  o.z = bfl(su.y) + acc0.z + acc1.z;
  o.w = bfh(su.y) + acc0.w + acc1.w;
  *(float4*)&t[(size_t)wid * HIDD + c] = o;
}

// -------- Node update GEMM: hb = relu(T @ W + b) written as bf16 --------

template <int K>
__global__ __launch_bounds__(256) void k_gemm_relu(const float* __restrict__ T,
                                                   const float* __restrict__ W,
                                                   const float* __restrict__ bias,
                                                   ushort* __restrict__ outb, int nrows) {
  __shared__ float tl[32][K];
  const int r0 = blockIdx.x * 32;
  const int tid = threadIdx.x;
  const int KV = K / 4;
  for (int i = tid; i < 32 * KV; i += 256) {
    int row = i / KV;
    int kk = (i - row * KV) * 4;
    float4 v = {0.f, 0.f, 0.f, 0.f};
    if (r0 + row < nrows) v = *(const float4*)&T[(size_t)(r0 + row) * K + kk];
    *(float4*)&tl[row][kk] = v;
  }
  __syncthreads();
  const int c = (tid & 63) * 4;
  const int rg = (tid >> 6) * 8;
  float4 acc[8];
#pragma unroll
  for (int r = 0; r < 8; ++r) acc[r] = make_float4(0.f, 0.f, 0.f, 0.f);
  for (int k = 0; k < K; ++k) {
    const float4 w = *(const float4*)&W[k * HIDD + c];
#pragma unroll
    for (int r = 0; r < 8; ++r) {
      float tv = tl[rg + r][k];
      acc[r].x = fmaf(tv, w.x, acc[r].x);
      acc[r].y = fmaf(tv, w.y, acc[r].y);
      acc[r].z = fmaf(tv, w.z, acc[r].z);
      acc[r].w = fmaf(tv, w.w, acc[r].w);
    }
  }
  const float4 bb = *(const float4*)&bias[c];
#pragma unroll
  for (int r = 0; r < 8; ++r) {
    int row = r0 + rg + r;
    if (row < nrows) {
      uint2 o;
      o.x = packbf(fmaxf(acc[r].x + bb.x, 0.f), fmaxf(acc[r].y + bb.y, 0.f));
      o.y = packbf(fmaxf(acc[r].z + bb.z, 0.f), fmaxf(acc[r].w + bb.w, 0.f));
      *(uint2*)&outb[(size_t)row * HIDD + c] = o;
    }
  }
}

// ---------------- Mean pool per graph (batch sorted, h in bf16) ---------------
// split each graph across PCH blocks; partials then reduced (no atomics)

__global__ void k_pool_partial(const ushort* __restrict__ hb, const int* __restrict__ batch,
                               float* __restrict__ fp) {  // fp[PCH][NGRAPH][HIDD]
  int b = blockIdx.x >> 3;
  int j = blockIdx.x & 7;
  __shared__ int srange[2];
  if (threadIdx.x < 2) {
    int target = b + threadIdx.x;
    int lo = 0, hi = NNODES;
    while (lo < hi) {
      int mid = (lo + hi) >> 1;
      if (batch[mid] < target) lo = mid + 1; else hi = mid;
    }
    srange[threadIdx.x] = lo;
  }
  __syncthreads();
  int s = srange[0], eend = srange[1];
  int len = eend - s;
  int cs = s + (int)((long long)len * j / PCH);
  int ce = s + (int)((long long)len * (j + 1) / PCH);
  int col = threadIdx.x;
  float acc = 0.f;
  for (int n = cs; n < ce; ++n) acc += bf1(hb[(size_t)n * HIDD + col]);
  fp[((size_t)j * NGRAPH + b) * HIDD + col] = acc;
}

__global__ void k_pool_final(const float* __restrict__ fp, const int* __restrict__ batch,
                             const float* __restrict__ gf, float* __restrict__ feats) {
  int b = blockIdx.x;
  __shared__ int srange[2];
  if (threadIdx.x < 2) {
    int target = b + threadIdx.x;
    int lo = 0, hi = NNODES;
    while (lo < hi) {
      int mid = (lo + hi) >> 1;
      if (batch[mid] < target) lo = mid + 1; else hi = mid;
    }
    srange[threadIdx.x] = lo;
  }
  __syncthreads();
  int col = threadIdx.x;
  float acc = 0.f;
#pragma unroll
  for (int j = 0; j < PCH; ++j) acc += fp[((size_t)j * NGRAPH + b) * HIDD + col];
  float cnt = fmaxf((float)(srange[1] - srange[0]), 1.0f);
  feats[b * FEATD + col] = acc / cnt;
  if (col < GDIM) feats[b * FEATD + HIDD + col] = gf[b * GDIM + col];
}

// ---------------- Heads: logits [B,64] then value [B] ----------------

__global__ void k_heads(const float* __restrict__ feats, const float* __restrict__ Wp,
                        const float* __restrict__ bp, const float* __restrict__ Wv,
                        const float* __restrict__ bv, float* __restrict__ out) {
  int b = blockIdx.x;
  int t = threadIdx.x;  // 64 threads = 1 wave
  __shared__ float f[FEATD];
  for (int i = t; i < FEATD; i += 64) f[i] = feats[b * FEATD + i];
  __syncthreads();
  float acc = bp[t];
  for (int k = 0; k < FEATD; ++k) acc = fmaf(f[k], Wp[k * NACT + t], acc);
  out[b * NACT + t] = acc;
  float pv = 0.f;
  for (int k = t; k < FEATD; k += 64) pv = fmaf(f[k], Wv[k], pv);
#pragma unroll
  for (int d = 32; d > 0; d >>= 1) pv += __shfl_down(pv, d);
  if (t == 0) out[NGRAPH * NACT + b] = pv + bv[0];
}

// ---------------- launch ----------------

extern "C" void kernel_launch(void* const* d_in, const int* in_sizes, int n_in,
                              void* d_out, int out_size, void* d_ws, size_t ws_size,
                              hipStream_t stream) {
  const float* x   = (const float*)d_in[0];
  const float* ea  = (const float*)d_in[1];
  const float* gf  = (const float*)d_in[2];
  const float* We0 = (const float*)d_in[3];
  const float* W0  = (const float*)d_in[4];
  const float* b0  = (const float*)d_in[5];
  const float* We  = (const float*)d_in[6];
  const float* W   = (const float*)d_in[7];
  const float* bb  = (const float*)d_in[8];
  const float* Wp  = (const float*)d_in[9];
  const float* bp  = (const float*)d_in[10];
  const float* Wv  = (const float*)d_in[11];
  const float* bv  = (const float*)d_in[12];
  const int* eidx  = (const int*)d_in[13];
  const int* batch = (const int*)d_in[14];
  const int* esrc = eidx;
  const int* edst = eidx + NEDGES;

  char* w = (char*)d_ws;
  size_t p = 0;
  auto take = [&](size_t bytes) {
    size_t r = p;
    p += (bytes + 255) & ~(size_t)255;
    return r;
  };
  int* off      = (int*)(w + take((NNODES + 1) * 4));
  int* cur      = (int*)(w + take(NNODES * 4));
  int* sums     = (int*)(w + take(1024));
  int* csr_src  = (int*)(w + take((size_t)NEDGES * 4));
  ushort* eab   = (ushort*)(w + take((size_t)NEDGES * FEDGE * 2));
  float* t0     = (float*)(w + take((size_t)NNODES * FNODE * 4));
  ushort* xb    = (ushort*)(w + take((size_t)NNODES * FNODE * 2));
  float* tbuf   = (float*)(w + take((size_t)NNODES * HIDD * 4));
  ushort* hb    = (ushort*)(w + take((size_t)NNODES * HIDD * 2));
  float* fp     = (float*)(w + take((size_t)PCH * NGRAPH * HIDD * 4));
  float* feats  = (float*)(w + take((size_t)NGRAPH * FEATD * 4));
  if (p > ws_size) return;  // workspace too small -> visible failure

  // CSR by dst (+ edge_attr reordered into CSR order as bf16)
  k_zero_i32<<<(NNODES + 1 + 255) / 256, 256, 0, stream>>>(off, NNODES + 1);
  k_hist<<<(NEDGES + 255) / 256, 256, 0, stream>>>(edst, off);
  int n_scan = NNODES + 1;
  int nb_scan = (n_scan + 1023) / 1024;
  k_scan1<<<nb_scan, 1024, 0, stream>>>(off, n_scan, sums);
  k_scan2<<<1, 1, 0, stream>>>(sums, nb_scan);
  k_scan3<<<nb_scan, 1024, 0, stream>>>(off, n_scan, sums);
  k_copy_i32<<<(NNODES + 255) / 256, 256, 0, stream>>>(off, cur, NNODES);
  k_scatter<<<(NEDGES + 255) / 256, 256, 0, stream>>>(esrc, edst, cur, ea, csr_src, eab);

  // x -> bf16 for the layer-0 gather
  k_cvt_x<<<(NNODES * FNODE / 4 + 255) / 256, 256, 0, stream>>>(x, xb);

  // layer 0
  k_edge32<<<NNODES / 4, 256, 0, stream>>>(x, xb, eab, We0, off, csr_src, t0);
  k_gemm_relu<FNODE><<<(NNODES + 31) / 32, 256, 0, stream>>>(t0, W0, b0, hb, NNODES);

  // layers 1..3: edge pull (bf16 gather) -> fp32 t -> GEMM -> bf16 h
  for (int l = 0; l < 3; ++l) {
    k_edge256<<<NNODES / 4, 256, 0, stream>>>(hb, eab, We + (size_t)l * FEDGE * HIDD, off,
                                              csr_src, tbuf);
    k_gemm_relu<HIDD><<<(NNODES + 31) / 32, 256, 0, stream>>>(
        tbuf, W + (size_t)l * HIDD * HIDD, bb + (size_t)l * HIDD, hb, NNODES);
  }

  // pool + heads
  k_pool_partial<<<NGRAPH * PCH, HIDD, 0, stream>>>(hb, batch, fp);
  k_pool_final<<<NGRAPH, HIDD, 0, stream>>>(fp, batch, gf, feats);
  k_heads<<<NGRAPH, 64, 0, stream>>>(feats, Wp, bp, Wv, bv, (float*)d_out);
}

// Round 4
// 825.306 us; speedup vs baseline: 2.0429x; 1.2972x over previous
//
#include <hip/hip_runtime.h>
#include <hip/hip_bf16.h>

#define NNODES 50000
#define NEDGES 1600000
#define FNODE 32
#define FEDGE 8
#define HIDD 256
#define NGRAPH 64
#define GDIM 16
#define NACT 64
#define FEATD (HIDD + GDIM) // 272
#define PCH 8               // pool chunks per graph

typedef short bf16x8 __attribute__((ext_vector_type(8)));
typedef float f32x4 __attribute__((ext_vector_type(4)));
typedef __bf16 bf16x2 __attribute__((ext_vector_type(2)));

// ---------------- bf16 helpers ----------------

__device__ inline float bfl(uint u) {  // low 16 bits -> float
  union { uint i; float f; } v; v.i = u << 16; return v.f;
}
__device__ inline float bfh(uint u) {  // high 16 bits -> float
  union { uint i; float f; } v; v.i = u & 0xffff0000u; return v.f;
}
__device__ inline float bf1(ushort u) {
  union { uint i; float f; } v; v.i = ((uint)u) << 16; return v.f;
}
__device__ inline ushort f2b(float a) {
  __hip_bfloat16 h = __float2bfloat16(a);  // RNE
  return *(ushort*)&h;
}
__device__ inline uint packbf(float a, float b) {
  return (uint)f2b(a) | ((uint)f2b(b) << 16);
}

// dot2: a.lo*b.lo + a.hi*b.hi + c  (packed bf16 pairs)
__device__ inline float dot2bf(uint a, uint b, float c) {
#if defined(__has_builtin)
#if __has_builtin(__builtin_amdgcn_fdot2_f32_bf16)
  union { uint u; bf16x2 v; } ua, ub;
  ua.u = a; ub.u = b;
  return __builtin_amdgcn_fdot2_f32_bf16(ua.v, ub.v, c, false);
#else
  return fmaf(bfl(a), bfl(b), fmaf(bfh(a), bfh(b), c));
#endif
#else
  return fmaf(bfl(a), bfl(b), fmaf(bfh(a), bfh(b), c));
#endif
}

// ---------------- CSR build ----------------

__global__ void k_zero_i32(int* __restrict__ p, int n) {
  int i = blockIdx.x * blockDim.x + threadIdx.x;
  if (i < n) p[i] = 0;
}

__global__ void k_hist(const int* __restrict__ dst, int* __restrict__ off) {
  int e = blockIdx.x * blockDim.x + threadIdx.x;
  if (e < NEDGES) atomicAdd(&off[dst[e] + 1], 1);
}

__global__ void k_scan1(int* __restrict__ data, int n, int* __restrict__ sums) {
  __shared__ int buf[1024];
  int gid = blockIdx.x * 1024 + threadIdx.x;
  int v = (gid < n) ? data[gid] : 0;
  buf[threadIdx.x] = v;
  __syncthreads();
  for (int d = 1; d < 1024; d <<= 1) {
    int t = (threadIdx.x >= d) ? buf[threadIdx.x - d] : 0;
    __syncthreads();
    buf[threadIdx.x] += t;
    __syncthreads();
  }
  if (gid < n) data[gid] = buf[threadIdx.x];
  if (threadIdx.x == 1023) sums[blockIdx.x] = buf[1023];
}

__global__ void k_scan2(int* __restrict__ sums, int nb) {
  int run = 0;
  for (int i = 0; i < nb; ++i) { run += sums[i]; sums[i] = run; }
}

__global__ void k_scan3(int* __restrict__ data, int n, const int* __restrict__ sums) {
  int gid = blockIdx.x * 1024 + threadIdx.x;
  if (blockIdx.x > 0 && gid < n) data[gid] += sums[blockIdx.x - 1];
}

__global__ void k_copy_i32(const int* __restrict__ a, int* __restrict__ b, int n) {
  int i = blockIdx.x * blockDim.x + threadIdx.x;
  if (i < n) b[i] = a[i];
}

// scatter edges into CSR order; also reorder edge_attr into CSR order as bf16
__global__ void k_scatter(const int* __restrict__ src, const int* __restrict__ dst,
                          int* __restrict__ cur, const float* __restrict__ ea,
                          int* __restrict__ csr_src, ushort* __restrict__ eab) {
  int e = blockIdx.x * blockDim.x + threadIdx.x;
  if (e >= NEDGES) return;
  int d = dst[e];
  int pos = atomicAdd(&cur[d], 1);
  csr_src[pos] = src[e];
  float4 a = *(const float4*)&ea[(size_t)e * FEDGE];
  float4 b = *(const float4*)&ea[(size_t)e * FEDGE + 4];
  uint4 o;
  o.x = packbf(a.x, a.y);
  o.y = packbf(a.z, a.w);
  o.z = packbf(b.x, b.y);
  o.w = packbf(b.z, b.w);
  *(uint4*)&eab[(size_t)pos * FEDGE] = o;
}

// ---------------- x -> bf16 ----------------

__global__ void k_cvt_x(const float* __restrict__ x, ushort* __restrict__ xb) {
  int i = blockIdx.x * blockDim.x + threadIdx.x;  // one float4 per thread
  if (i >= NNODES * FNODE / 4) return;
  float4 v = *(const float4*)&x[(size_t)i * 4];
  uint2 o;
  o.x = packbf(v.x, v.y);
  o.y = packbf(v.z, v.w);
  *(uint2*)&xb[(size_t)i * 4] = o;
}

// ---------------- weight packing ----------------
// wep0[k2*32 + c]  = (We0[2k2][c], We0[2k2+1][c]) bf16 pair
// wep[l*1024 + k2*256 + c] likewise for We[l]
__global__ void k_pack_wep(const float* __restrict__ We0, const float* __restrict__ We,
                           uint* __restrict__ wep0, uint* __restrict__ wep) {
  int t = blockIdx.x * blockDim.x + threadIdx.x;
  if (t < 128) {
    int k2 = t >> 5, c = t & 31;
    wep0[t] = packbf(We0[(2 * k2) * FNODE + c], We0[(2 * k2 + 1) * FNODE + c]);
  } else if (t < 128 + 3 * 1024) {
    int u = t - 128;
    int l = u >> 10;
    int r = u & 1023;
    int k2 = r >> 8, c = r & 255;
    const float* Wl = We + (size_t)l * FEDGE * HIDD;
    wep[u] = packbf(Wl[(2 * k2) * HIDD + c], Wl[(2 * k2 + 1) * HIDD + c]);
  }
}

// MFMA B-fragment packing: Wp[frag*64*8 + lane*8 + i] = W[ks*32+(lane>>4)*8+i][nf*16+(lane&15)]
__global__ void k_pack_w(const float* __restrict__ W0, const float* __restrict__ W,
                         ushort* __restrict__ wp0, ushort* __restrict__ wp) {
  int t = blockIdx.x * blockDim.x + threadIdx.x;
  if (t < 1024) {  // layer 0, K=32 (ks=0)
    int lane = t & 63;
    int nf = t >> 6;
    int col = nf * 16 + (lane & 15);
    int k0 = (lane >> 4) * 8;
    ushort o[8];
#pragma unroll
    for (int i = 0; i < 8; ++i) o[i] = f2b(W0[(size_t)(k0 + i) * HIDD + col]);
    *(uint4*)&wp0[(size_t)t * 8] = *(uint4*)o;
  } else if (t < 1024 + 3 * 8192) {
    int u = t - 1024;
    int l = u / 8192;
    int r = u - l * 8192;
    int lane = r & 63;
    int frag = r >> 6;  // ks*16+nf
    int nf = frag & 15, ks = frag >> 4;
    int col = nf * 16 + (lane & 15);
    int k0 = ks * 32 + (lane >> 4) * 8;
    const float* Wl = W + (size_t)l * HIDD * HIDD;
    ushort o[8];
#pragma unroll
    for (int i = 0; i < 8; ++i) o[i] = f2b(Wl[(size_t)(k0 + i) * HIDD + col]);
    *(uint4*)&wp[(size_t)u * 8] = *(uint4*)o;
  }
}

// ---------------- Layer 0 edge pull (d=32), dot2 + uniform edge data ----------

__global__ __launch_bounds__(256) void k_edge32(
    const float* __restrict__ x, const ushort* __restrict__ xb,
    const uint4* __restrict__ eab4, const uint* __restrict__ wep0,
    const int* __restrict__ off, const int* __restrict__ csr_src,
    ushort* __restrict__ t0b) {
  int wid = __builtin_amdgcn_readfirstlane(
      (int)((blockIdx.x * blockDim.x + threadIdx.x) >> 6));
  if (wid >= NNODES) return;
  int lane = threadIdx.x & 63;
  int j = lane >> 5;
  int c = lane & 31;
  uint w0 = wep0[c], w1 = wep0[32 + c], w2 = wep0[64 + c], w3 = wep0[96 + c];
  int s0 = off[wid], s1 = off[wid + 1];
  float acc = 0.f;
  int e = s0;
  for (; e + 2 <= s1; e += 2) {  // halves of the wave take alternate edges
    int sA = csr_src[e], sB = csr_src[e + 1];      // uniform (scalar)
    uint4 Ea = eab4[e], Eb = eab4[e + 1];          // uniform (scalar)
    int s = j ? sB : sA;
    uint4 eu;
    eu.x = j ? Eb.x : Ea.x;
    eu.y = j ? Eb.y : Ea.y;
    eu.z = j ? Eb.z : Ea.z;
    eu.w = j ? Eb.w : Ea.w;
    float pr = bf1(xb[(size_t)s * FNODE + c]);
    pr = dot2bf(eu.x, w0, pr);
    pr = dot2bf(eu.y, w1, pr);
    pr = dot2bf(eu.z, w2, pr);
    pr = dot2bf(eu.w, w3, pr);
    acc += fmaxf(pr, 0.f);
  }
  if (e < s1) {  // odd tail edge -> half 0 only
    if (j == 0) {
      int s = csr_src[e];
      uint4 eu = eab4[e];
      float pr = bf1(xb[(size_t)s * FNODE + c]);
      pr = dot2bf(eu.x, w0, pr);
      pr = dot2bf(eu.y, w1, pr);
      pr = dot2bf(eu.z, w2, pr);
      pr = dot2bf(eu.w, w3, pr);
      acc += fmaxf(pr, 0.f);
    }
  }
  acc += __shfl_xor(acc, 32);
  if (j == 0) t0b[wid * FNODE + c] = f2b(x[wid * FNODE + c] + acc);
}

// ---------------- Layers 1-3 edge pull (d=256), dot2 + scalar edge data -------

__device__ inline void body_dot(uint2 hu, uint4 eu, const uint4 wq[4], float4& acc) {
  float4 pr;
  pr.x = bfl(hu.x);
  pr.y = bfh(hu.x);
  pr.z = bfl(hu.y);
  pr.w = bfh(hu.y);
  pr.x = dot2bf(eu.x, wq[0].x, pr.x);
  pr.x = dot2bf(eu.y, wq[1].x, pr.x);
  pr.x = dot2bf(eu.z, wq[2].x, pr.x);
  pr.x = dot2bf(eu.w, wq[3].x, pr.x);
  pr.y = dot2bf(eu.x, wq[0].y, pr.y);
  pr.y = dot2bf(eu.y, wq[1].y, pr.y);
  pr.y = dot2bf(eu.z, wq[2].y, pr.y);
  pr.y = dot2bf(eu.w, wq[3].y, pr.y);
  pr.z = dot2bf(eu.x, wq[0].z, pr.z);
  pr.z = dot2bf(eu.y, wq[1].z, pr.z);
  pr.z = dot2bf(eu.z, wq[2].z, pr.z);
  pr.z = dot2bf(eu.w, wq[3].z, pr.z);
  pr.w = dot2bf(eu.x, wq[0].w, pr.w);
  pr.w = dot2bf(eu.y, wq[1].w, pr.w);
  pr.w = dot2bf(eu.z, wq[2].w, pr.w);
  pr.w = dot2bf(eu.w, wq[3].w, pr.w);
  acc.x += fmaxf(pr.x, 0.f);
  acc.y += fmaxf(pr.y, 0.f);
  acc.z += fmaxf(pr.z, 0.f);
  acc.w += fmaxf(pr.w, 0.f);
}

__global__ __launch_bounds__(256) void k_edge256(
    const ushort* __restrict__ hb, const uint4* __restrict__ eab4,
    const uint* __restrict__ wepl, const int* __restrict__ off,
    const int* __restrict__ csr_src, ushort* __restrict__ tb) {
  int wid = __builtin_amdgcn_readfirstlane(
      (int)((blockIdx.x * blockDim.x + threadIdx.x) >> 6));
  if (wid >= NNODES) return;
  int lane = threadIdx.x & 63;
  int c = lane * 4;
  uint4 wq[4];
#pragma unroll
  for (int k2 = 0; k2 < 4; ++k2) wq[k2] = *(const uint4*)&wepl[k2 * HIDD + c];
  const int4* csr4 = (const int4*)csr_src;
  int s0 = off[wid], s1 = off[wid + 1];
  float4 acc0 = {0.f, 0.f, 0.f, 0.f}, acc1 = {0.f, 0.f, 0.f, 0.f};
  int e = s0;
  for (; e < s1 && (e & 3); ++e) {  // align to 4 for int4 csr reads
    int s = csr_src[e];
    uint4 eu = eab4[e];
    uint2 hu = *(const uint2*)&hb[(size_t)s * HIDD + c];
    body_dot(hu, eu, wq, acc0);
  }
  for (; e + 8 <= s1; e += 8) {  // 8 h-gathers in flight; edge data scalar
    int4 sa = csr4[e >> 2];
    int4 sb = csr4[(e >> 2) + 1];
    uint2 h0 = *(const uint2*)&hb[(size_t)sa.x * HIDD + c];
    uint2 h1 = *(const uint2*)&hb[(size_t)sa.y * HIDD + c];
    uint2 h2 = *(const uint2*)&hb[(size_t)sa.z * HIDD + c];
    uint2 h3 = *(const uint2*)&hb[(size_t)sa.w * HIDD + c];
    uint2 h4 = *(const uint2*)&hb[(size_t)sb.x * HIDD + c];
    uint2 h5 = *(const uint2*)&hb[(size_t)sb.y * HIDD + c];
    uint2 h6 = *(const uint2*)&hb[(size_t)sb.z * HIDD + c];
    uint2 h7 = *(const uint2*)&hb[(size_t)sb.w * HIDD + c];
    uint4 E0 = eab4[e + 0], E1 = eab4[e + 1], E2 = eab4[e + 2], E3 = eab4[e + 3];
    uint4 E4 = eab4[e + 4], E5 = eab4[e + 5], E6 = eab4[e + 6], E7 = eab4[e + 7];
    body_dot(h0, E0, wq, acc0);
    body_dot(h1, E1, wq, acc1);
    body_dot(h2, E2, wq, acc0);
    body_dot(h3, E3, wq, acc1);
    body_dot(h4, E4, wq, acc0);
    body_dot(h5, E5, wq, acc1);
    body_dot(h6, E6, wq, acc0);
    body_dot(h7, E7, wq, acc1);
  }
  for (; e < s1; ++e) {
    int s = csr_src[e];
    uint4 eu = eab4[e];
    uint2 hu = *(const uint2*)&hb[(size_t)s * HIDD + c];
    body_dot(hu, eu, wq, acc0);
  }

  uint2 su = *(const uint2*)&hb[(size_t)wid * HIDD + c];  // self term (bf16)
  float4 o;
  o.x = bfl(su.x) + acc0.x + acc1.x;
  o.y = bfh(su.x) + acc0.y + acc1.y;
  o.z = bfl(su.y) + acc0.z + acc1.z;
  o.w = bfh(su.y) + acc0.w + acc1.w;
  uint2 ob;
  ob.x = packbf(o.x, o.y);
  ob.y = packbf(o.z, o.w);
  *(uint2*)&tb[(size_t)wid * HIDD + c] = ob;
}

// -------- MFMA node-update GEMM: outb = relu(Tb @ W + b), all bf16 I/O --------
// block: 256 thr = 4 waves; tile M=64 (16 rows/wave), N=256, K template.
// A staged in LDS with XOR chunk swizzle; B read from packed Wp fragments.

template <int K>
__global__ __launch_bounds__(256) void k_gemm_mfma(
    const ushort* __restrict__ Tb, const ushort* __restrict__ Wp,
    const float* __restrict__ bias, ushort* __restrict__ outb, int nrows) {
  constexpr int CPR = K / 8;          // 16-byte chunks per row
  constexpr int SWZ = (CPR - 1) & 7;  // XOR swizzle mask
  __shared__ ushort tl[64 * K];
  const int tid = threadIdx.x;
  const int r0 = blockIdx.x * 64;
  for (int ch = tid; ch < 64 * CPR; ch += 256) {
    int row = ch / CPR;
    int cb = ch - row * CPR;
    uint4 v = make_uint4(0, 0, 0, 0);
    if (r0 + row < nrows) v = *(const uint4*)&Tb[(size_t)(r0 + row) * K + cb * 8];
    *(uint4*)&tl[(size_t)(row * CPR + (cb ^ (row & SWZ))) * 8] = v;
  }
  __syncthreads();
  const int wave = tid >> 6;
  const int lane = tid & 63;
  const int arow = wave * 16 + (lane & 15);
  const int kgrp = lane >> 4;  // 0..3
  f32x4 acc[16];
#pragma unroll
  for (int nf = 0; nf < 16; ++nf) acc[nf] = (f32x4){0.f, 0.f, 0.f, 0.f};
#pragma unroll
  for (int ks = 0; ks < K / 32; ++ks) {
    int cb = ks * 4 + kgrp;
    bf16x8 af = *(const bf16x8*)&tl[(size_t)(arow * CPR + (cb ^ (arow & SWZ))) * 8];
#pragma unroll
    for (int nf = 0; nf < 16; ++nf) {
      bf16x8 bfg = *(const bf16x8*)&Wp[(((size_t)ks * 16 + nf) * 64 + lane) * 8];
      acc[nf] = __builtin_amdgcn_mfma_f32_16x16x32_bf16(af, bfg, acc[nf], 0, 0, 0);
    }
  }
  const int ocol0 = lane & 15;
  const int orow0 = r0 + wave * 16 + (lane >> 4) * 4;
#pragma unroll
  for (int nf = 0; nf < 16; ++nf) {
    int col = nf * 16 + ocol0;
    float bv = bias[col];
#pragma unroll
    for (int r = 0; r < 4; ++r) {
      int row = orow0 + r;
      if (row < nrows) outb[(size_t)row * HIDD + col] = f2b(fmaxf(acc[nf][r] + bv, 0.f));
    }
  }
}

// ---------------- Mean pool per graph (batch sorted, h in bf16) ---------------

__global__ void k_pool_partial(const ushort* __restrict__ hb, const int* __restrict__ batch,
                               float* __restrict__ fp) {  // fp[PCH][NGRAPH][HIDD]
  int b = blockIdx.x >> 3;
  int j = blockIdx.x & 7;
  __shared__ int srange[2];
  if (threadIdx.x < 2) {
    int target = b + threadIdx.x;
    int lo = 0, hi = NNODES;
    while (lo < hi) {
      int mid = (lo + hi) >> 1;
      if (batch[mid] < target) lo = mid + 1; else hi = mid;
    }
    srange[threadIdx.x] = lo;
  }
  __syncthreads();
  int s = srange[0], eend = srange[1];
  int len = eend - s;
  int cs = s + (int)((long long)len * j / PCH);
  int ce = s + (int)((long long)len * (j + 1) / PCH);
  int col = threadIdx.x;
  float acc = 0.f;
  for (int n = cs; n < ce; ++n) acc += bf1(hb[(size_t)n * HIDD + col]);
  fp[((size_t)j * NGRAPH + b) * HIDD + col] = acc;
}

__global__ void k_pool_final(const float* __restrict__ fp, const int* __restrict__ batch,
                             const float* __restrict__ gf, float* __restrict__ feats) {
  int b = blockIdx.x;
  __shared__ int srange[2];
  if (threadIdx.x < 2) {
    int target = b + threadIdx.x;
    int lo = 0, hi = NNODES;
    while (lo < hi) {
      int mid = (lo + hi) >> 1;
      if (batch[mid] < target) lo = mid + 1; else hi = mid;
    }
    srange[threadIdx.x] = lo;
  }
  __syncthreads();
  int col = threadIdx.x;
  float acc = 0.f;
#pragma unroll
  for (int j = 0; j < PCH; ++j) acc += fp[((size_t)j * NGRAPH + b) * HIDD + col];
  float cnt = fmaxf((float)(srange[1] - srange[0]), 1.0f);
  feats[b * FEATD + col] = acc / cnt;
  if (col < GDIM) feats[b * FEATD + HIDD + col] = gf[b * GDIM + col];
}

// ---------------- Heads: logits [B,64] then value [B] ----------------

__global__ void k_heads(const float* __restrict__ feats, const float* __restrict__ Wp,
                        const float* __restrict__ bp, const float* __restrict__ Wv,
                        const float* __restrict__ bv, float* __restrict__ out) {
  int b = blockIdx.x;
  int t = threadIdx.x;  // 64 threads = 1 wave
  __shared__ float f[FEATD];
  for (int i = t; i < FEATD; i += 64) f[i] = feats[b * FEATD + i];
  __syncthreads();
  float acc = bp[t];
  for (int k = 0; k < FEATD; ++k) acc = fmaf(f[k], Wp[k * NACT + t], acc);
  out[b * NACT + t] = acc;
  float pv = 0.f;
  for (int k = t; k < FEATD; k += 64) pv = fmaf(f[k], Wv[k], pv);
#pragma unroll
  for (int d = 32; d > 0; d >>= 1) pv += __shfl_down(pv, d);
  if (t == 0) out[NGRAPH * NACT + b] = pv + bv[0];
}

// ---------------- launch ----------------

extern "C" void kernel_launch(void* const* d_in, const int* in_sizes, int n_in,
                              void* d_out, int out_size, void* d_ws, size_t ws_size,
                              hipStream_t stream) {
  const float* x   = (const float*)d_in[0];
  const float* ea  = (const float*)d_in[1];
  const float* gf  = (const float*)d_in[2];
  const float* We0 = (const float*)d_in[3];
  const float* W0  = (const float*)d_in[4];
  const float* b0  = (const float*)d_in[5];
  const float* We  = (const float*)d_in[6];
  const float* W   = (const float*)d_in[7];
  const float* bb  = (const float*)d_in[8];
  const float* Wp  = (const float*)d_in[9];
  const float* bp  = (const float*)d_in[10];
  const float* Wv  = (const float*)d_in[11];
  const float* bv  = (const float*)d_in[12];
  const int* eidx  = (const int*)d_in[13];
  const int* batch = (const int*)d_in[14];
  const int* esrc = eidx;
  const int* edst = eidx + NEDGES;

  char* w = (char*)d_ws;
  size_t p = 0;
  auto take = [&](size_t bytes) {
    size_t r = p;
    p += (bytes + 255) & ~(size_t)255;
    return r;
  };
  int* off      = (int*)(w + take((NNODES + 1) * 4));
  int* cur      = (int*)(w + take(NNODES * 4));
  int* sums     = (int*)(w + take(1024));
  int* csr_src  = (int*)(w + take((size_t)NEDGES * 4));
  ushort* eab   = (ushort*)(w + take((size_t)NEDGES * FEDGE * 2));
  ushort* t0b   = (ushort*)(w + take((size_t)NNODES * FNODE * 2));
  ushort* xb    = (ushort*)(w + take((size_t)NNODES * FNODE * 2));
  ushort* tb    = (ushort*)(w + take((size_t)NNODES * HIDD * 2));
  ushort* hb    = (ushort*)(w + take((size_t)NNODES * HIDD * 2));
  uint* wep0    = (uint*)(w + take(128 * 4));
  uint* wepb    = (uint*)(w + take(3 * 1024 * 4));
  ushort* wp0   = (ushort*)(w + take((size_t)1024 * 8 * 2));
  ushort* wpb   = (ushort*)(w + take((size_t)3 * 8192 * 8 * 2));
  float* fp     = (float*)(w + take((size_t)PCH * NGRAPH * HIDD * 4));
  float* feats  = (float*)(w + take((size_t)NGRAPH * FEATD * 4));
  if (p > ws_size) return;  // workspace too small -> visible failure

  // CSR by dst (+ edge_attr reordered into CSR order as bf16)
  k_zero_i32<<<(NNODES + 1 + 255) / 256, 256, 0, stream>>>(off, NNODES + 1);
  k_hist<<<(NEDGES + 255) / 256, 256, 0, stream>>>(edst, off);
  int n_scan = NNODES + 1;
  int nb_scan = (n_scan + 1023) / 1024;
  k_scan1<<<nb_scan, 1024, 0, stream>>>(off, n_scan, sums);
  k_scan2<<<1, 1, 0, stream>>>(sums, nb_scan);
  k_scan3<<<nb_scan, 1024, 0, stream>>>(off, n_scan, sums);
  k_copy_i32<<<(NNODES + 255) / 256, 256, 0, stream>>>(off, cur, NNODES);
  k_scatter<<<(NEDGES + 255) / 256, 256, 0, stream>>>(esrc, edst, cur, ea, csr_src, eab);

  // weight packs + x -> bf16
  k_pack_wep<<<(128 + 3 * 1024 + 255) / 256, 256, 0, stream>>>(We0, We, wep0, wepb);
  k_pack_w<<<(1024 + 3 * 8192 + 255) / 256, 256, 0, stream>>>(W0, W, wp0, wpb);
  k_cvt_x<<<(NNODES * FNODE / 4 + 255) / 256, 256, 0, stream>>>(x, xb);

  const int gemm_grid = (NNODES + 63) / 64;

  // layer 0
  k_edge32<<<NNODES / 4, 256, 0, stream>>>(x, xb, (const uint4*)eab, wep0, off,
                                           csr_src, t0b);
  k_gemm_mfma<FNODE><<<gemm_grid, 256, 0, stream>>>(t0b, wp0, b0, hb, NNODES);

  // layers 1..3: edge pull (bf16 gather, dot2) -> bf16 t -> MFMA GEMM -> bf16 h
  for (int l = 0; l < 3; ++l) {
    k_edge256<<<NNODES / 4, 256, 0, stream>>>(hb, (const uint4*)eab, wepb + l * 1024,
                                              off, csr_src, tb);
    k_gemm_mfma<HIDD><<<gemm_grid, 256, 0, stream>>>(
        tb, wpb + (size_t)l * 8192 * 8, bb + (size_t)l * HIDD, hb, NNODES);
  }

  // pool + heads
  k_pool_partial<<<NGRAPH * PCH, HIDD, 0, stream>>>(hb, batch, fp);
  k_pool_final<<<NGRAPH, HIDD, 0, stream>>>(fp, batch, gf, feats);
  k_heads<<<NGRAPH, 64, 0, stream>>>(feats, Wp, bp, Wv, bv, (float*)d_out);
}

// Round 5
// 749.386 us; speedup vs baseline: 2.2498x; 1.1013x over previous
//
#include <hip/hip_runtime.h>
#include <hip/hip_bf16.h>

#define NNODES 50000
#define NEDGES 1600000
#define FNODE 32
#define FEDGE 8
#define HIDD 256
#define NGRAPH 64
#define GDIM 16
#define NACT 64
#define FEATD (HIDD + GDIM) // 272
#define PCH 8               // pool chunks per graph

typedef short bf16x8 __attribute__((ext_vector_type(8)));
typedef float f32x4 __attribute__((ext_vector_type(4)));
typedef __bf16 bf16x2 __attribute__((ext_vector_type(2)));

// ---------------- bf16 helpers ----------------

__device__ inline float bfl(uint u) {  // low 16 bits -> float
  union { uint i; float f; } v; v.i = u << 16; return v.f;
}
__device__ inline float bfh(uint u) {  // high 16 bits -> float
  union { uint i; float f; } v; v.i = u & 0xffff0000u; return v.f;
}
__device__ inline float bf1(ushort u) {
  union { uint i; float f; } v; v.i = ((uint)u) << 16; return v.f;
}
__device__ inline ushort f2b(float a) {
  __hip_bfloat16 h = __float2bfloat16(a);  // RNE
  return *(ushort*)&h;
}
__device__ inline uint packbf(float a, float b) {
  return (uint)f2b(a) | ((uint)f2b(b) << 16);
}

// dot2: a.lo*b.lo + a.hi*b.hi + c  (packed bf16 pairs)
__device__ inline float dot2bf(uint a, uint b, float c) {
#if defined(__has_builtin)
#if __has_builtin(__builtin_amdgcn_fdot2_f32_bf16)
  union { uint u; bf16x2 v; } ua, ub;
  ua.u = a; ub.u = b;
  return __builtin_amdgcn_fdot2_f32_bf16(ua.v, ub.v, c, false);
#else
  return fmaf(bfl(a), bfl(b), fmaf(bfh(a), bfh(b), c));
#endif
#else
  return fmaf(bfl(a), bfl(b), fmaf(bfh(a), bfh(b), c));
#endif
}

// ---------------- CSR build ----------------

__global__ void k_zero_i32(int* __restrict__ p, int n) {
  int i = blockIdx.x * blockDim.x + threadIdx.x;
  if (i < n) p[i] = 0;
}

__global__ void k_hist(const int* __restrict__ dst, int* __restrict__ off) {
  int e = blockIdx.x * blockDim.x + threadIdx.x;
  if (e < NEDGES) atomicAdd(&off[dst[e] + 1], 1);
}

__global__ void k_scan1(int* __restrict__ data, int n, int* __restrict__ sums) {
  __shared__ int buf[1024];
  int gid = blockIdx.x * 1024 + threadIdx.x;
  int v = (gid < n) ? data[gid] : 0;
  buf[threadIdx.x] = v;
  __syncthreads();
  for (int d = 1; d < 1024; d <<= 1) {
    int t = (threadIdx.x >= d) ? buf[threadIdx.x - d] : 0;
    __syncthreads();
    buf[threadIdx.x] += t;
    __syncthreads();
  }
  if (gid < n) data[gid] = buf[threadIdx.x];
  if (threadIdx.x == 1023) sums[blockIdx.x] = buf[1023];
}

__global__ void k_scan2(int* __restrict__ sums, int nb) {
  int run = 0;
  for (int i = 0; i < nb; ++i) { run += sums[i]; sums[i] = run; }
}

// scan3 + cur-copy fused
__global__ void k_scan3(int* __restrict__ data, int n, const int* __restrict__ sums,
                        int* __restrict__ cur) {
  int gid = blockIdx.x * 1024 + threadIdx.x;
  if (gid < n) {
    int v = data[gid];
    if (blockIdx.x > 0) v += sums[blockIdx.x - 1];
    data[gid] = v;
    if (gid < NNODES) cur[gid] = v;
  }
}

// scatter edges into CSR order; also reorder edge_attr into CSR order as bf16
__global__ void k_scatter(const int* __restrict__ src, const int* __restrict__ dst,
                          int* __restrict__ cur, const float* __restrict__ ea,
                          int* __restrict__ csr_src, ushort* __restrict__ eab) {
  int e = blockIdx.x * blockDim.x + threadIdx.x;
  if (e >= NEDGES) return;
  int d = dst[e];
  int pos = atomicAdd(&cur[d], 1);
  csr_src[pos] = src[e];
  float4 a = *(const float4*)&ea[(size_t)e * FEDGE];
  float4 b = *(const float4*)&ea[(size_t)e * FEDGE + 4];
  uint4 o;
  o.x = packbf(a.x, a.y);
  o.y = packbf(a.z, a.w);
  o.z = packbf(b.x, b.y);
  o.w = packbf(b.z, b.w);
  *(uint4*)&eab[(size_t)pos * FEDGE] = o;
}

// ---------------- x -> bf16 ----------------

__global__ void k_cvt_x(const float* __restrict__ x, ushort* __restrict__ xb) {
  int i = blockIdx.x * blockDim.x + threadIdx.x;  // one float4 per thread
  if (i >= NNODES * FNODE / 4) return;
  float4 v = *(const float4*)&x[(size_t)i * 4];
  uint2 o;
  o.x = packbf(v.x, v.y);
  o.y = packbf(v.z, v.w);
  *(uint2*)&xb[(size_t)i * 4] = o;
}

// ---------------- weight packing ----------------

__global__ void k_pack_wep(const float* __restrict__ We0, const float* __restrict__ We,
                           uint* __restrict__ wep0, uint* __restrict__ wep) {
  int t = blockIdx.x * blockDim.x + threadIdx.x;
  if (t < 128) {
    int k2 = t >> 5, c = t & 31;
    wep0[t] = packbf(We0[(2 * k2) * FNODE + c], We0[(2 * k2 + 1) * FNODE + c]);
  } else if (t < 128 + 3 * 1024) {
    int u = t - 128;
    int l = u >> 10;
    int r = u & 1023;
    int k2 = r >> 8, c = r & 255;
    const float* Wl = We + (size_t)l * FEDGE * HIDD;
    wep[u] = packbf(Wl[(2 * k2) * HIDD + c], Wl[(2 * k2 + 1) * HIDD + c]);
  }
}

// MFMA B-fragment packing: Wp[frag*64*8 + lane*8 + i] = W[ks*32+(lane>>4)*8+i][nf*16+(lane&15)]
__global__ void k_pack_w(const float* __restrict__ W0, const float* __restrict__ W,
                         ushort* __restrict__ wp0, ushort* __restrict__ wp) {
  int t = blockIdx.x * blockDim.x + threadIdx.x;
  if (t < 1024) {  // layer 0, K=32 (ks=0)
    int lane = t & 63;
    int nf = t >> 6;
    int col = nf * 16 + (lane & 15);
    int k0 = (lane >> 4) * 8;
    ushort o[8];
#pragma unroll
    for (int i = 0; i < 8; ++i) o[i] = f2b(W0[(size_t)(k0 + i) * HIDD + col]);
    *(uint4*)&wp0[(size_t)t * 8] = *(uint4*)o;
  } else if (t < 1024 + 3 * 8192) {
    int u = t - 1024;
    int l = u / 8192;
    int r = u - l * 8192;
    int lane = r & 63;
    int frag = r >> 6;  // ks*16+nf
    int nf = frag & 15, ks = frag >> 4;
    int col = nf * 16 + (lane & 15);
    int k0 = ks * 32 + (lane >> 4) * 8;
    const float* Wl = W + (size_t)l * HIDD * HIDD;
    ushort o[8];
#pragma unroll
    for (int i = 0; i < 8; ++i) o[i] = f2b(Wl[(size_t)(k0 + i) * HIDD + col]);
    *(uint4*)&wp[(size_t)u * 8] = *(uint4*)o;
  }
}

// ---------------- Layer 0 edge pull (d=32), dot2, 4 edges/half in flight ------

__global__ __launch_bounds__(256) void k_edge32(
    const float* __restrict__ x, const ushort* __restrict__ xb,
    const uint4* __restrict__ eab4, const uint* __restrict__ wep0,
    const int* __restrict__ off, const int* __restrict__ csr_src,
    ushort* __restrict__ t0b) {
  int wid = __builtin_amdgcn_readfirstlane(
      (int)((blockIdx.x * blockDim.x + threadIdx.x) >> 6));
  if (wid >= NNODES) return;
  int lane = threadIdx.x & 63;
  int j = lane >> 5;
  int c = lane & 31;
  uint w0 = wep0[c], w1 = wep0[32 + c], w2 = wep0[64 + c], w3 = wep0[96 + c];
  int s0 = off[wid], s1 = off[wid + 1];
  float acc = 0.f;
  int e = s0 + j;
  for (; e + 6 < s1; e += 8) {  // 4 edges per half-wave in flight
    int sA = csr_src[e], sB = csr_src[e + 2], sC = csr_src[e + 4], sD = csr_src[e + 6];
    ushort hA = xb[(size_t)sA * FNODE + c];
    ushort hB = xb[(size_t)sB * FNODE + c];
    ushort hC = xb[(size_t)sC * FNODE + c];
    ushort hD = xb[(size_t)sD * FNODE + c];
    uint4 eA = eab4[e];
    uint4 eB = eab4[e + 2];
    uint4 eC = eab4[e + 4];
    uint4 eD = eab4[e + 6];
    float pr;
#define B32(hu, eu)                 \
    pr = bf1(hu);                   \
    pr = dot2bf(eu.x, w0, pr);      \
    pr = dot2bf(eu.y, w1, pr);      \
    pr = dot2bf(eu.z, w2, pr);      \
    pr = dot2bf(eu.w, w3, pr);      \
    acc += fmaxf(pr, 0.f);
    B32(hA, eA) B32(hB, eB) B32(hC, eC) B32(hD, eD)
  }
  for (; e < s1; e += 2) {
    int s = csr_src[e];
    ushort hu = xb[(size_t)s * FNODE + c];
    uint4 eu = eab4[e];
    float pr;
    B32(hu, eu)
#undef B32
  }
  acc += __shfl_xor(acc, 32);
  if (j == 0) t0b[wid * FNODE + c] = f2b(x[wid * FNODE + c] + acc);
}

// ---------------- Layers 1-3 edge pull (d=256), 16-deep gather pipeline -------

__device__ inline void body_dot(uint2 hu, uint4 eu, const uint4 wq[4], float4& acc) {
  float4 pr;
  pr.x = bfl(hu.x);
  pr.y = bfh(hu.x);
  pr.z = bfl(hu.y);
  pr.w = bfh(hu.y);
  pr.x = dot2bf(eu.x, wq[0].x, pr.x);
  pr.x = dot2bf(eu.y, wq[1].x, pr.x);
  pr.x = dot2bf(eu.z, wq[2].x, pr.x);
  pr.x = dot2bf(eu.w, wq[3].x, pr.x);
  pr.y = dot2bf(eu.x, wq[0].y, pr.y);
  pr.y = dot2bf(eu.y, wq[1].y, pr.y);
  pr.y = dot2bf(eu.z, wq[2].y, pr.y);
  pr.y = dot2bf(eu.w, wq[3].y, pr.y);
  pr.z = dot2bf(eu.x, wq[0].z, pr.z);
  pr.z = dot2bf(eu.y, wq[1].z, pr.z);
  pr.z = dot2bf(eu.z, wq[2].z, pr.z);
  pr.z = dot2bf(eu.w, wq[3].z, pr.z);
  pr.w = dot2bf(eu.x, wq[0].w, pr.w);
  pr.w = dot2bf(eu.y, wq[1].w, pr.w);
  pr.w = dot2bf(eu.z, wq[2].w, pr.w);
  pr.w = dot2bf(eu.w, wq[3].w, pr.w);
  acc.x += fmaxf(pr.x, 0.f);
  acc.y += fmaxf(pr.y, 0.f);
  acc.z += fmaxf(pr.z, 0.f);
  acc.w += fmaxf(pr.w, 0.f);
}

// U edges: issue all gathers, then compute (static indices via full unroll)
#define EDGE_BLOCK(U)                                                       \
  for (; e + (U) <= s1; e += (U)) {                                         \
    int s[U];                                                               \
    uint2 h[U];                                                             \
    uint4 E[U];                                                             \
    _Pragma("unroll") for (int u = 0; u < (U); ++u) s[u] = csr_src[e + u];  \
    _Pragma("unroll") for (int u = 0; u < (U); ++u)                         \
        h[u] = *(const uint2*)&hb[(size_t)s[u] * HIDD + c];                 \
    _Pragma("unroll") for (int u = 0; u < (U); ++u) E[u] = eab4[e + u];     \
    _Pragma("unroll") for (int u = 0; u < (U); ++u)                         \
        body_dot(h[u], E[u], wq, (u & 1) ? acc1 : acc0);                    \
  }

__global__ __launch_bounds__(256) void k_edge256(
    const ushort* __restrict__ hb, const uint4* __restrict__ eab4,
    const uint* __restrict__ wepl, const int* __restrict__ off,
    const int* __restrict__ csr_src, ushort* __restrict__ tb) {
  int wid = __builtin_amdgcn_readfirstlane(
      (int)((blockIdx.x * blockDim.x + threadIdx.x) >> 6));
  if (wid >= NNODES) return;
  int lane = threadIdx.x & 63;
  int c = lane * 4;
  uint4 wq[4];
#pragma unroll
  for (int k2 = 0; k2 < 4; ++k2) wq[k2] = *(const uint4*)&wepl[k2 * HIDD + c];
  int s0 = off[wid], s1 = off[wid + 1];
  float4 acc0 = {0.f, 0.f, 0.f, 0.f}, acc1 = {0.f, 0.f, 0.f, 0.f};
  int e = s0;
  EDGE_BLOCK(16)
  EDGE_BLOCK(8)
  EDGE_BLOCK(4)
  for (; e < s1; ++e) {
    int s = csr_src[e];
    uint2 hu = *(const uint2*)&hb[(size_t)s * HIDD + c];
    uint4 eu = eab4[e];
    body_dot(hu, eu, wq, acc0);
  }

  uint2 su = *(const uint2*)&hb[(size_t)wid * HIDD + c];  // self term (bf16)
  float4 o;
  o.x = bfl(su.x) + acc0.x + acc1.x;
  o.y = bfh(su.x) + acc0.y + acc1.y;
  o.z = bfl(su.y) + acc0.z + acc1.z;
  o.w = bfh(su.y) + acc0.w + acc1.w;
  uint2 ob;
  ob.x = packbf(o.x, o.y);
  ob.y = packbf(o.z, o.w);
  *(uint2*)&tb[(size_t)wid * HIDD + c] = ob;
}
#undef EDGE_BLOCK

// -------- MFMA node-update GEMM: outb = relu(Tb @ W + b), all bf16 I/O --------
// block: 512 thr = 8 waves; tile M=128 (16 rows/wave), N=256, K template.
// A staged in LDS with XOR chunk swizzle; B read from packed Wp fragments.

template <int K>
__global__ __launch_bounds__(512) void k_gemm_mfma(
    const ushort* __restrict__ Tb, const ushort* __restrict__ Wp,
    const float* __restrict__ bias, ushort* __restrict__ outb, int nrows) {
  constexpr int CPR = K / 8;          // 16-byte chunks per row
  constexpr int SWZ = (CPR - 1) & 7;  // XOR swizzle mask
  __shared__ ushort tl[128 * K];      // 64KB at K=256
  const int tid = threadIdx.x;
  const int r0 = blockIdx.x * 128;
  for (int ch = tid; ch < 128 * CPR; ch += 512) {
    int row = ch / CPR;
    int cb = ch - row * CPR;
    uint4 v = make_uint4(0, 0, 0, 0);
    if (r0 + row < nrows) v = *(const uint4*)&Tb[(size_t)(r0 + row) * K + cb * 8];
    *(uint4*)&tl[(size_t)(row * CPR + (cb ^ (row & SWZ))) * 8] = v;
  }
  __syncthreads();
  const int wave = tid >> 6;
  const int lane = tid & 63;
  const int arow = wave * 16 + (lane & 15);
  const int kgrp = lane >> 4;  // 0..3
  f32x4 acc[16];
#pragma unroll
  for (int nf = 0; nf < 16; ++nf) acc[nf] = (f32x4){0.f, 0.f, 0.f, 0.f};
#pragma unroll
  for (int ks = 0; ks < K / 32; ++ks) {
    int cb = ks * 4 + kgrp;
    bf16x8 af = *(const bf16x8*)&tl[(size_t)(arow * CPR + (cb ^ (arow & SWZ))) * 8];
#pragma unroll
    for (int nf = 0; nf < 16; ++nf) {
      bf16x8 bfg = *(const bf16x8*)&Wp[(((size_t)ks * 16 + nf) * 64 + lane) * 8];
      acc[nf] = __builtin_amdgcn_mfma_f32_16x16x32_bf16(af, bfg, acc[nf], 0, 0, 0);
    }
  }
  const int ocol0 = lane & 15;
  const int orow0 = r0 + wave * 16 + (lane >> 4) * 4;
#pragma unroll
  for (int nf = 0; nf < 16; ++nf) {
    int col = nf * 16 + ocol0;
    float bv = bias[col];
#pragma unroll
    for (int r = 0; r < 4; ++r) {
      int row = orow0 + r;
      if (row < nrows) outb[(size_t)row * HIDD + col] = f2b(fmaxf(acc[nf][r] + bv, 0.f));
    }
  }
}

// ---------------- Mean pool per graph (batch sorted, h in bf16) ---------------

__global__ void k_pool_partial(const ushort* __restrict__ hb, const int* __restrict__ batch,
                               float* __restrict__ fp) {  // fp[PCH][NGRAPH][HIDD]
  int b = blockIdx.x >> 3;
  int j = blockIdx.x & 7;
  __shared__ int srange[2];
  if (threadIdx.x < 2) {
    int target = b + threadIdx.x;
    int lo = 0, hi = NNODES;
    while (lo < hi) {
      int mid = (lo + hi) >> 1;
      if (batch[mid] < target) lo = mid + 1; else hi = mid;
    }
    srange[threadIdx.x] = lo;
  }
  __syncthreads();
  int s = srange[0], eend = srange[1];
  int len = eend - s;
  int cs = s + (int)((long long)len * j / PCH);
  int ce = s + (int)((long long)len * (j + 1) / PCH);
  int col = threadIdx.x;
  float acc = 0.f;
  for (int n = cs; n < ce; ++n) acc += bf1(hb[(size_t)n * HIDD + col]);
  fp[((size_t)j * NGRAPH + b) * HIDD + col] = acc;
}

__global__ void k_pool_final(const float* __restrict__ fp, const int* __restrict__ batch,
                             const float* __restrict__ gf, float* __restrict__ feats) {
  int b = blockIdx.x;
  __shared__ int srange[2];
  if (threadIdx.x < 2) {
    int target = b + threadIdx.x;
    int lo = 0, hi = NNODES;
    while (lo < hi) {
      int mid = (lo + hi) >> 1;
      if (batch[mid] < target) lo = mid + 1; else hi = mid;
    }
    srange[threadIdx.x] = lo;
  }
  __syncthreads();
  int col = threadIdx.x;
  float acc = 0.f;
#pragma unroll
  for (int j = 0; j < PCH; ++j) acc += fp[((size_t)j * NGRAPH + b) * HIDD + col];
  float cnt = fmaxf((float)(srange[1] - srange[0]), 1.0f);
  feats[b * FEATD + col] = acc / cnt;
  if (col < GDIM) feats[b * FEATD + HIDD + col] = gf[b * GDIM + col];
}

// ---------------- Heads: logits [B,64] then value [B] ----------------

__global__ void k_heads(const float* __restrict__ feats, const float* __restrict__ Wp,
                        const float* __restrict__ bp, const float* __restrict__ Wv,
                        const float* __restrict__ bv, float* __restrict__ out) {
  int b = blockIdx.x;
  int t = threadIdx.x;  // 64 threads = 1 wave
  __shared__ float f[FEATD];
  for (int i = t; i < FEATD; i += 64) f[i] = feats[b * FEATD + i];
  __syncthreads();
  float acc = bp[t];
  for (int k = 0; k < FEATD; ++k) acc = fmaf(f[k], Wp[k * NACT + t], acc);
  out[b * NACT + t] = acc;
  float pv = 0.f;
  for (int k = t; k < FEATD; k += 64) pv = fmaf(f[k], Wv[k], pv);
#pragma unroll
  for (int d = 32; d > 0; d >>= 1) pv += __shfl_down(pv, d);
  if (t == 0) out[NGRAPH * NACT + b] = pv + bv[0];
}

// ---------------- launch ----------------

extern "C" void kernel_launch(void* const* d_in, const int* in_sizes, int n_in,
                              void* d_out, int out_size, void* d_ws, size_t ws_size,
                              hipStream_t stream) {
  const float* x   = (const float*)d_in[0];
  const float* ea  = (const float*)d_in[1];
  const float* gf  = (const float*)d_in[2];
  const float* We0 = (const float*)d_in[3];
  const float* W0  = (const float*)d_in[4];
  const float* b0  = (const float*)d_in[5];
  const float* We  = (const float*)d_in[6];
  const float* W   = (const float*)d_in[7];
  const float* bb  = (const float*)d_in[8];
  const float* Wp  = (const float*)d_in[9];
  const float* bp  = (const float*)d_in[10];
  const float* Wv  = (const float*)d_in[11];
  const float* bv  = (const float*)d_in[12];
  const int* eidx  = (const int*)d_in[13];
  const int* batch = (const int*)d_in[14];
  const int* esrc = eidx;
  const int* edst = eidx + NEDGES;

  char* w = (char*)d_ws;
  size_t p = 0;
  auto take = [&](size_t bytes) {
    size_t r = p;
    p += (bytes + 255) & ~(size_t)255;
    return r;
  };
  int* off      = (int*)(w + take((NNODES + 1) * 4));
  int* cur      = (int*)(w + take(NNODES * 4));
  int* sums     = (int*)(w + take(1024));
  int* csr_src  = (int*)(w + take((size_t)NEDGES * 4));
  ushort* eab   = (ushort*)(w + take((size_t)NEDGES * FEDGE * 2));
  ushort* t0b   = (ushort*)(w + take((size_t)NNODES * FNODE * 2));
  ushort* xb    = (ushort*)(w + take((size_t)NNODES * FNODE * 2));
  ushort* tb    = (ushort*)(w + take((size_t)NNODES * HIDD * 2));
  ushort* hb    = (ushort*)(w + take((size_t)NNODES * HIDD * 2));
  uint* wep0    = (uint*)(w + take(128 * 4));
  uint* wepb    = (uint*)(w + take(3 * 1024 * 4));
  ushort* wp0   = (ushort*)(w + take((size_t)1024 * 8 * 2));
  ushort* wpb   = (ushort*)(w + take((size_t)3 * 8192 * 8 * 2));
  float* fp     = (float*)(w + take((size_t)PCH * NGRAPH * HIDD * 4));
  float* feats  = (float*)(w + take((size_t)NGRAPH * FEATD * 4));
  if (p > ws_size) return;  // workspace too small -> visible failure

  // CSR by dst (+ edge_attr reordered into CSR order as bf16)
  k_zero_i32<<<(NNODES + 1 + 255) / 256, 256, 0, stream>>>(off, NNODES + 1);
  k_hist<<<(NEDGES + 255) / 256, 256, 0, stream>>>(edst, off);
  int n_scan = NNODES + 1;
  int nb_scan = (n_scan + 1023) / 1024;
  k_scan1<<<nb_scan, 1024, 0, stream>>>(off, n_scan, sums);
  k_scan2<<<1, 1, 0, stream>>>(sums, nb_scan);
  k_scan3<<<nb_scan, 1024, 0, stream>>>(off, n_scan, sums, cur);
  k_scatter<<<(NEDGES + 255) / 256, 256, 0, stream>>>(esrc, edst, cur, ea, csr_src, eab);

  // weight packs + x -> bf16
  k_pack_wep<<<(128 + 3 * 1024 + 255) / 256, 256, 0, stream>>>(We0, We, wep0, wepb);
  k_pack_w<<<(1024 + 3 * 8192 + 255) / 256, 256, 0, stream>>>(W0, W, wp0, wpb);
  k_cvt_x<<<(NNODES * FNODE / 4 + 255) / 256, 256, 0, stream>>>(x, xb);

  const int gemm_grid = (NNODES + 127) / 128;

  // layer 0
  k_edge32<<<NNODES / 4, 256, 0, stream>>>(x, xb, (const uint4*)eab, wep0, off,
                                           csr_src, t0b);
  k_gemm_mfma<FNODE><<<gemm_grid, 512, 0, stream>>>(t0b, wp0, b0, hb, NNODES);

  // layers 1..3: edge pull (bf16 gather, dot2) -> bf16 t -> MFMA GEMM -> bf16 h
  for (int l = 0; l < 3; ++l) {
    k_edge256<<<NNODES / 4, 256, 0, stream>>>(hb, (const uint4*)eab, wepb + l * 1024,
                                              off, csr_src, tb);
    k_gemm_mfma<HIDD><<<gemm_grid, 512, 0, stream>>>(
        tb, wpb + (size_t)l * 8192 * 8, bb + (size_t)l * HIDD, hb, NNODES);
  }

  // pool + heads
  k_pool_partial<<<NGRAPH * PCH, HIDD, 0, stream>>>(hb, batch, fp);
  k_pool_final<<<NGRAPH, HIDD, 0, stream>>>(fp, batch, gf, feats);
  k_heads<<<NGRAPH, 64, 0, stream>>>(feats, Wp, bp, Wv, bv, (float*)d_out);
}